// Round 6
// baseline (381.998 us; speedup 1.0000x reference)
//
#include <hip/hip_runtime.h>
#include <hip/hip_bf16.h>

// Problem: B=16, S=1024, IN=512, OUT=256.
// out = softmax((x@wq^T + bq)(x@wk^T + bk)^T / sqrt(512)) @ (x@wv^T + bv)
// RoPE cancels (same rotation applied to q and k) -> skipped.
// Two kernels: qkv_gemm (fp32 in, inline bf16 cvt, T14 load/compute overlap;
// writes q scaled+biased, k biased, v transposed) -> attn (4-way in-block
// split-K flash, 1024 thr = 16 waves = 4 grps x 4 waves, 4 waves/SIMD).

typedef __attribute__((ext_vector_type(8))) short short8;
typedef __attribute__((ext_vector_type(4))) short short4v;
typedef __attribute__((ext_vector_type(4))) float f32x4;

#define GLL16(g, l)                                                            \
  __builtin_amdgcn_global_load_lds(                                            \
      (const __attribute__((address_space(1))) unsigned int*)(g),              \
      (__attribute__((address_space(3))) unsigned int*)(l), 16, 0, 0)

static __device__ __forceinline__ short f2bf(float f) {
  __hip_bfloat16 h = __float2bfloat16(f);
  return __builtin_bit_cast(short, h);
}

// ---------------- QKV GEMM ----------------
// C[16384 x 768] = x[16384 x 512] @ w[768 x 512]^T, fp32 in, bf16 MFMA.
// 128x128 tile, BK=64, 4 waves (2x2), wave = 64x64 = 4x4 frags of 16x16x32.
// T14 pipeline: loads for tile kk+1 issued before MFMA(kk), latency hidden.
__global__ __launch_bounds__(256) void qkv_gemm(
    const float* __restrict__ x, const float* __restrict__ wq,
    const float* __restrict__ wk, const float* __restrict__ wv,
    const float* __restrict__ bq, const float* __restrict__ bk,
    const float* __restrict__ bv, short* __restrict__ qb,
    short* __restrict__ kb, short* __restrict__ vt) {
  __shared__ __align__(16) char smem[32768];
  const int bid = blockIdx.x;                   // 768 blocks
  const int swz = (bid & 7) * 96 + (bid >> 3);  // XCD chunking (768 % 8 == 0)
  const int mt = swz / 6, nt = swz % 6;
  const int tid = threadIdx.x;
  const int w = tid >> 6, lane = tid & 63;
  const int g = lane >> 4, c = lane & 15;
  const int wm = w >> 1, wn = w & 1;

  const float* wsel = (nt < 2) ? wq : (nt < 4) ? wk : wv;
  const int wro = (nt & 1) * 128;

  f32x4 acc[4][4];
  const f32x4 fzero = {0.f, 0.f, 0.f, 0.f};
#pragma unroll
  for (int mi = 0; mi < 4; mi++)
#pragma unroll
    for (int ni = 0; ni < 4; ni++) acc[mi][ni] = fzero;

  const int arow = tid >> 4;   // 0..15
  const int acol4 = tid & 15;  // float4 index within 64-wide k slice
  const int achunk = acol4 >> 1, ahalf = (tid & 1) * 8;

  float4 xv[8], wv8[8];
#pragma unroll
  for (int j = 0; j < 8; j++) {  // prologue load kk=0
    int row = j * 16 + arow;
    xv[j] = *(const float4*)(x + (mt * 128 + row) * 512 + acol4 * 4);
    wv8[j] = *(const float4*)(wsel + (wro + row) * 512 + acol4 * 4);
  }

  for (int kk = 0; kk < 8; ++kk) {
    __syncthreads();
#pragma unroll
    for (int j = 0; j < 8; j++) {
      int row = j * 16 + arow;
      short4v s4;
      s4[0] = f2bf(xv[j].x); s4[1] = f2bf(xv[j].y);
      s4[2] = f2bf(xv[j].z); s4[3] = f2bf(xv[j].w);
      *(short4v*)(smem + row * 128 + ((achunk ^ (row & 7)) * 16) + ahalf) = s4;
      short4v t4;
      t4[0] = f2bf(wv8[j].x); t4[1] = f2bf(wv8[j].y);
      t4[2] = f2bf(wv8[j].z); t4[3] = f2bf(wv8[j].w);
      *(short4v*)(smem + 16384 + row * 128 + ((achunk ^ (row & 7)) * 16) + ahalf) = t4;
    }
    __syncthreads();
    if (kk < 7) {  // issue next tile's loads; latency hides under MFMA below
#pragma unroll
      for (int j = 0; j < 8; j++) {
        int row = j * 16 + arow;
        xv[j] = *(const float4*)(x + (mt * 128 + row) * 512 + (kk + 1) * 64 + acol4 * 4);
        wv8[j] = *(const float4*)(wsel + (wro + row) * 512 + (kk + 1) * 64 + acol4 * 4);
      }
    }
#pragma unroll
    for (int ks = 0; ks < 2; ++ks) {
      short8 af[4], bf[4];
#pragma unroll
      for (int mi = 0; mi < 4; mi++) {
        int row = wm * 64 + mi * 16 + c;
        af[mi] = *(const short8*)(smem + row * 128 + (((ks * 4 + g) ^ (row & 7)) * 16));
      }
#pragma unroll
      for (int ni = 0; ni < 4; ni++) {
        int row = wn * 64 + ni * 16 + c;
        bf[ni] = *(const short8*)(smem + 16384 + row * 128 + (((ks * 4 + g) ^ (row & 7)) * 16));
      }
#pragma unroll
      for (int mi = 0; mi < 4; mi++)
#pragma unroll
        for (int ni = 0; ni < 4; ni++)
          acc[mi][ni] = __builtin_amdgcn_mfma_f32_16x16x32_bf16(af[mi], bf[ni], acc[mi][ni], 0, 0, 0);
    }
  }

  // epilogue — C/D layout: col = lane&15, row = (lane>>4)*4 + reg
  const int cls = nt >> 1;                  // 0=q 1=k 2=v (block-uniform)
  const int cw = (nt & 1) * 128 + wn * 64;  // col base within 256-wide matrix
  const int rowbase = mt * 128 + wm * 64;
  if (cls == 0) {
#pragma unroll
    for (int ni = 0; ni < 4; ni++) {
      int col = cw + ni * 16 + c;
      float bias = bq[col];
#pragma unroll
      for (int mi = 0; mi < 4; mi++)
#pragma unroll
        for (int j = 0; j < 4; j++) {
          int row = rowbase + mi * 16 + g * 4 + j;
          qb[row * 256 + col] = f2bf((acc[mi][ni][j] + bias) * 0.044194173824159216f);
        }
    }
  } else if (cls == 1) {
#pragma unroll
    for (int ni = 0; ni < 4; ni++) {
      int col = cw + ni * 16 + c;
      float bias = bk[col];
#pragma unroll
      for (int mi = 0; mi < 4; mi++)
#pragma unroll
        for (int j = 0; j < 4; j++) {
          int row = rowbase + mi * 16 + g * 4 + j;
          kb[row * 256 + col] = f2bf(acc[mi][ni][j] + bias);
        }
    }
  } else {
    // v: per-wave 64(s) x 64(d) transpose through LDS, then coalesced stores
    __syncthreads();
    char* tb = smem + w * 8192;
#pragma unroll
    for (int ni = 0; ni < 4; ni++) {
      int dl = ni * 16 + c;
      float bias = bv[cw + dl];
#pragma unroll
      for (int mi = 0; mi < 4; mi++)
#pragma unroll
        for (int j = 0; j < 4; j++) {
          int sl = mi * 16 + g * 4 + j;
          *(short*)(tb + dl * 128 + ((sl * 2) ^ ((dl & 7) << 4))) =
              f2bf(acc[mi][ni][j] + bias);
        }
    }
    const int bb = rowbase >> 10, sb = rowbase & 1023;
#pragma unroll
    for (int i = 0; i < 8; i++) {
      int dl = i * 8 + (lane >> 3);
      int ch = lane & 7;
      short8 val = *(const short8*)(tb + dl * 128 + ((ch ^ (dl & 7)) * 16));
      *(short8*)(vt + (bb * 256 + cw + dl) * 1024 + sb + ch * 8) = val;
    }
  }
}

// ---------------- flash attention, 4-way in-block split-K ----------------
// grid 256 = 16 batches x 16 q-tiles(64 rows); 1024 threads = 16 waves.
// grp = w>>2 (4 grps x 256 keys); lw = w&3 (q-rows lw*16..+15, same all grps).
// kt tile = 32 keys; 8 iters. LDS: K[4][16K] | V[4][16K] | P 16x1280 | ml.
// End: 4-way merge, chunked over d-halves through the K/V LDS region.
__global__ __launch_bounds__(1024, 4) void attn_kernel(
    const short* __restrict__ qb, const short* __restrict__ kb,
    const short* __restrict__ vt, float* __restrict__ out) {
  __shared__ __align__(16) char smem[153088];
  const int bid = blockIdx.x;
  const int swz = (bid & 7) * 32 + (bid >> 3);  // 2 batches per XCD chunk
  const int b = swz >> 4, qt = swz & 15;
  const int tid = threadIdx.x;
  const int w = tid >> 6, lane = tid & 63;
  const int grp = w >> 2, lw = w & 3;
  const int g = lane >> 4, c = lane & 15;
  const int q0 = b * 1024 + qt * 64 + lw * 16;
  char* kbase = smem + grp * 16384;            // [32 keys][512 B]
  char* vbase = smem + 65536 + grp * 16384;    // [256 d][64 B]
  short* sp = (short*)(smem + 131072 + w * 1280);  // P [16][40]

  // Q in registers (A-frags, 8 k-steps of 32 dims) — same rows all grps
  short8 qf[8];
#pragma unroll
  for (int ks = 0; ks < 8; ks++)
    qf[ks] = *(const short8*)(qb + (q0 + c) * 256 + ks * 32 + g * 8);

  f32x4 O[16];
  const f32x4 fzero = {0.f, 0.f, 0.f, 0.f};
#pragma unroll
  for (int ni = 0; ni < 16; ni++) O[ni] = fzero;
  float m_[4] = {-1e30f, -1e30f, -1e30f, -1e30f};
  float l_[4] = {0.f, 0.f, 0.f, 0.f};

  const int krow0 = b * 1024 + grp * 256;

  for (int kt = 0; kt < 8; ++kt) {
    __syncthreads();
    // stage K tile: 16 glls over 4 waves (4 each)
#pragma unroll
    for (int i = 0; i < 4; i++) {
      int j = lw * 4 + i;                 // 0..15, 2 rows per gll
      int r = j * 2 + (lane >> 5);
      int cc = lane & 31;
      GLL16(kb + (krow0 + kt * 32 + r) * 256 + ((cc ^ (r & 7)) * 8),
            kbase + j * 1024);
    }
    // stage V tile: 16 glls over 4 waves (4 each)
#pragma unroll
    for (int i = 0; i < 4; i++) {
      int j = lw * 4 + i;                 // 0..15, 16 rows per gll
      int r = j * 16 + (lane >> 2);
      int cc = lane & 3;
      GLL16(vt + (b * 256 + r) * 1024 + grp * 256 + kt * 32 + ((cc ^ (r & 3)) * 8),
            vbase + j * 1024);
    }
    asm volatile("s_waitcnt vmcnt(0)" ::: "memory");
    __syncthreads();

    // QK^T: S[16 rows x 32 keys] per wave
    f32x4 Sf[2];
    Sf[0] = fzero; Sf[1] = fzero;
#pragma unroll
    for (int ks = 0; ks < 8; ks++) {
      short8 kf[2];
#pragma unroll
      for (int nf = 0; nf < 2; nf++) {
        int key = nf * 16 + c;
        kf[nf] = *(const short8*)(kbase + key * 512 + (((ks * 4 + g) ^ (key & 7)) * 16));
      }
#pragma unroll
      for (int nf = 0; nf < 2; nf++)
        Sf[nf] = __builtin_amdgcn_mfma_f32_16x16x32_bf16(qf[ks], kf[nf], Sf[nf], 0, 0, 0);
    }

    // online softmax; lane holds rows 4g+j, keys c and c+16
    float tm[4];
#pragma unroll
    for (int j = 0; j < 4; j++) {
      float t = fmaxf(Sf[0][j], Sf[1][j]);
      t = fmaxf(t, __shfl_xor(t, 1));
      t = fmaxf(t, __shfl_xor(t, 2));
      t = fmaxf(t, __shfl_xor(t, 4));
      t = fmaxf(t, __shfl_xor(t, 8));
      tm[j] = t;
    }
    bool need = (tm[0] > m_[0] + 8.f) || (tm[1] > m_[1] + 8.f) ||
                (tm[2] > m_[2] + 8.f) || (tm[3] > m_[3] + 8.f);
    float Pv[2][4];
    if (__any(need)) {
      // full rescale path
      float scl[4];
#pragma unroll
      for (int j = 0; j < 4; j++) {
        float nm = fmaxf(m_[j], tm[j]);
        scl[j] = __expf(m_[j] - nm);
        m_[j] = nm;
        float rs = 0.f;
#pragma unroll
        for (int nf = 0; nf < 2; nf++) {
          float p = __expf(Sf[nf][j] - nm);
          Pv[nf][j] = p;
          rs += p;
        }
        rs += __shfl_xor(rs, 1);
        rs += __shfl_xor(rs, 2);
        rs += __shfl_xor(rs, 4);
        rs += __shfl_xor(rs, 8);
        l_[j] = l_[j] * scl[j] + rs;
      }
#pragma unroll
      for (int ni = 0; ni < 16; ni++) {
        O[ni][0] *= scl[0]; O[ni][1] *= scl[1];
        O[ni][2] *= scl[2]; O[ni][3] *= scl[3];
      }
    } else {
      // defer-max: keep m_, no O rescale; P bounded by e^8
#pragma unroll
      for (int j = 0; j < 4; j++) {
        float rs = 0.f;
#pragma unroll
        for (int nf = 0; nf < 2; nf++) {
          float p = __expf(Sf[nf][j] - m_[j]);
          Pv[nf][j] = p;
          rs += p;
        }
        rs += __shfl_xor(rs, 1);
        rs += __shfl_xor(rs, 2);
        rs += __shfl_xor(rs, 4);
        rs += __shfl_xor(rs, 8);
        l_[j] += rs;
      }
    }

    // P (bf16) -> per-wave LDS [16][40] -> A-frag (same wave, lgkm only)
#pragma unroll
    for (int nf = 0; nf < 2; nf++)
#pragma unroll
      for (int j = 0; j < 4; j++)
        sp[(g * 4 + j) * 40 + nf * 16 + c] = f2bf(Pv[nf][j]);

    short8 pf = *(const short8*)((char*)sp + c * 80 + g * 16);

    // PV: O[16 rows x 256 d] += P[16x32] @ V[32x256]
#pragma unroll
    for (int ni = 0; ni < 16; ni++) {
      int d = ni * 16 + c;
      short8 vf = *(const short8*)(vbase + d * 64 + ((g ^ (d & 3)) * 16));
      O[ni] = __builtin_amdgcn_mfma_f32_16x16x32_bf16(pf, vf, O[ni], 0, 0, 0);
    }
  }

  // ---- 4-way merge, chunked over d halves (reuses K/V LDS region) ----
  __syncthreads();  // all waves done with K/V tiles
  float2* mlb = (float2*)(smem + 151552);
  if (grp != 0) {
    char* reg0 = smem + ((grp - 1) * 4 + lw) * 8192;
#pragma unroll
    for (int ni = 0; ni < 8; ni++)
      *(f32x4*)(reg0 + ni * 1024 + c * 64 + g * 16) = O[ni];
#pragma unroll
    for (int j = 0; j < 4; j++) {
      float2 ml; ml.x = m_[j]; ml.y = l_[j];
      mlb[((grp - 1) * 4 + lw) * 16 + g * 4 + j] = ml;
    }
  }
  __syncthreads();
  float as[3][4], inv[4];
  if (grp == 0) {
    float mm[4];
    float2 mls[3][4];
#pragma unroll
    for (int j = 0; j < 4; j++) {
      mm[j] = m_[j];
#pragma unroll
      for (int s = 0; s < 3; s++) {
        mls[s][j] = mlb[(s * 4 + lw) * 16 + g * 4 + j];
        mm[j] = fmaxf(mm[j], mls[s][j].x);
      }
      float a0 = __expf(m_[j] - mm[j]);
      float lsum = a0 * l_[j];
#pragma unroll
      for (int s = 0; s < 3; s++) {
        as[s][j] = __expf(mls[s][j].x - mm[j]);
        lsum += as[s][j] * mls[s][j].y;
      }
      inv[j] = 1.0f / lsum;
      // fold a0 into O now (frees a0)
#pragma unroll
      for (int ni = 0; ni < 16; ni++) O[ni][j] *= a0;
    }
    // phase A: combine + store d 0..127
#pragma unroll
    for (int ni = 0; ni < 8; ni++) {
      f32x4 acc2 = O[ni];
#pragma unroll
      for (int s = 0; s < 3; s++) {
        f32x4 o2 = *(const f32x4*)(smem + (s * 4 + lw) * 8192 + ni * 1024 + c * 64 + g * 16);
        acc2[0] += as[s][0] * o2[0]; acc2[1] += as[s][1] * o2[1];
        acc2[2] += as[s][2] * o2[2]; acc2[3] += as[s][3] * o2[3];
      }
#pragma unroll
      for (int j = 0; j < 4; j++)
        out[(q0 + g * 4 + j) * 256 + ni * 16 + c] = acc2[j] * inv[j];
    }
  }
  __syncthreads();
  if (grp != 0) {
    char* reg0 = smem + ((grp - 1) * 4 + lw) * 8192;
#pragma unroll
    for (int ni = 8; ni < 16; ni++)
      *(f32x4*)(reg0 + (ni - 8) * 1024 + c * 64 + g * 16) = O[ni];
  }
  __syncthreads();
  if (grp == 0) {
    // phase B: combine + store d 128..255
#pragma unroll
    for (int ni = 8; ni < 16; ni++) {
      f32x4 acc2 = O[ni];
#pragma unroll
      for (int s = 0; s < 3; s++) {
        f32x4 o2 = *(const f32x4*)(smem + (s * 4 + lw) * 8192 + (ni - 8) * 1024 + c * 64 + g * 16);
        acc2[0] += as[s][0] * o2[0]; acc2[1] += as[s][1] * o2[1];
        acc2[2] += as[s][2] * o2[2]; acc2[3] += as[s][3] * o2[3];
      }
#pragma unroll
      for (int j = 0; j < 4; j++)
        out[(q0 + g * 4 + j) * 256 + ni * 16 + c] = acc2[j] * inv[j];
    }
  }
}

extern "C" void kernel_launch(void* const* d_in, const int* in_sizes, int n_in,
                              void* d_out, int out_size, void* d_ws, size_t ws_size,
                              hipStream_t stream) {
  const float* x  = (const float*)d_in[0];
  const float* wq = (const float*)d_in[1];
  const float* bq = (const float*)d_in[2];
  const float* wk = (const float*)d_in[3];
  const float* bk = (const float*)d_in[4];
  const float* wv = (const float*)d_in[5];
  const float* bv = (const float*)d_in[6];
  float* out = (float*)d_out;
  char* ws = (char*)d_ws;
  // ws layout (bytes): qb 8,388,608 | kb 8,388,608 | vt 8,388,608
  short* qb = (short*)ws;
  short* kb = (short*)(ws + 8388608);
  short* vt = (short*)(ws + 16777216);

  qkv_gemm<<<768, 256, 0, stream>>>(x, wq, wk, wv, bq, bk, bv, qb, kb, vt);
  attn_kernel<<<256, 1024, 0, stream>>>(qb, kb, vt, out);
}

// Round 7
// 294.046 us; speedup vs baseline: 1.2991x; 1.2991x over previous
//
#include <hip/hip_runtime.h>
#include <hip/hip_bf16.h>

// Problem: B=16, S=1024, IN=512, OUT=256.
// out = softmax((x@wq^T + bq)(x@wk^T + bk)^T / sqrt(512)) @ (x@wv^T + bv)
// RoPE cancels (same rotation applied to q and k) -> skipped.
// qkv_gemm: fp32 in, inline bf16 cvt, T14 prefetch; writes q(scaled+bias),
//           k(bias), v transposed (vt[b][d][s]).
// attn: 2-way in-block split-K flash, 512 thr; K double-buffered in LDS
//       (1 barrier/iter, prefetch under compute); V read direct from L2
//       into registers (L2-resident, no staging); LDS merge of halves.

typedef __attribute__((ext_vector_type(8))) short short8;
typedef __attribute__((ext_vector_type(4))) short short4v;
typedef __attribute__((ext_vector_type(4))) float f32x4;

#define GLL16(g, l)                                                            \
  __builtin_amdgcn_global_load_lds(                                            \
      (const __attribute__((address_space(1))) unsigned int*)(g),              \
      (__attribute__((address_space(3))) unsigned int*)(l), 16, 0, 0)

static __device__ __forceinline__ short f2bf(float f) {
  __hip_bfloat16 h = __float2bfloat16(f);
  return __builtin_bit_cast(short, h);
}

// ---------------- QKV GEMM (unchanged from round 4; passed) ----------------
__global__ __launch_bounds__(256) void qkv_gemm(
    const float* __restrict__ x, const float* __restrict__ wq,
    const float* __restrict__ wk, const float* __restrict__ wv,
    const float* __restrict__ bq, const float* __restrict__ bk,
    const float* __restrict__ bv, short* __restrict__ qb,
    short* __restrict__ kb, short* __restrict__ vt) {
  __shared__ __align__(16) char smem[32768];
  const int bid = blockIdx.x;                   // 768 blocks
  const int swz = (bid & 7) * 96 + (bid >> 3);  // XCD chunking (768 % 8 == 0)
  const int mt = swz / 6, nt = swz % 6;
  const int tid = threadIdx.x;
  const int w = tid >> 6, lane = tid & 63;
  const int g = lane >> 4, c = lane & 15;
  const int wm = w >> 1, wn = w & 1;

  const float* wsel = (nt < 2) ? wq : (nt < 4) ? wk : wv;
  const int wro = (nt & 1) * 128;

  f32x4 acc[4][4];
  const f32x4 fzero = {0.f, 0.f, 0.f, 0.f};
#pragma unroll
  for (int mi = 0; mi < 4; mi++)
#pragma unroll
    for (int ni = 0; ni < 4; ni++) acc[mi][ni] = fzero;

  const int arow = tid >> 4;   // 0..15
  const int acol4 = tid & 15;  // float4 index within 64-wide k slice
  const int achunk = acol4 >> 1, ahalf = (tid & 1) * 8;

  float4 xv[8], wv8[8];
#pragma unroll
  for (int j = 0; j < 8; j++) {  // prologue load kk=0
    int row = j * 16 + arow;
    xv[j] = *(const float4*)(x + (mt * 128 + row) * 512 + acol4 * 4);
    wv8[j] = *(const float4*)(wsel + (wro + row) * 512 + acol4 * 4);
  }

  for (int kk = 0; kk < 8; ++kk) {
    __syncthreads();
#pragma unroll
    for (int j = 0; j < 8; j++) {
      int row = j * 16 + arow;
      short4v s4;
      s4[0] = f2bf(xv[j].x); s4[1] = f2bf(xv[j].y);
      s4[2] = f2bf(xv[j].z); s4[3] = f2bf(xv[j].w);
      *(short4v*)(smem + row * 128 + ((achunk ^ (row & 7)) * 16) + ahalf) = s4;
      short4v t4;
      t4[0] = f2bf(wv8[j].x); t4[1] = f2bf(wv8[j].y);
      t4[2] = f2bf(wv8[j].z); t4[3] = f2bf(wv8[j].w);
      *(short4v*)(smem + 16384 + row * 128 + ((achunk ^ (row & 7)) * 16) + ahalf) = t4;
    }
    __syncthreads();
    if (kk < 7) {  // issue next tile's loads; latency hides under MFMA below
#pragma unroll
      for (int j = 0; j < 8; j++) {
        int row = j * 16 + arow;
        xv[j] = *(const float4*)(x + (mt * 128 + row) * 512 + (kk + 1) * 64 + acol4 * 4);
        wv8[j] = *(const float4*)(wsel + (wro + row) * 512 + (kk + 1) * 64 + acol4 * 4);
      }
    }
#pragma unroll
    for (int ks = 0; ks < 2; ++ks) {
      short8 af[4], bf[4];
#pragma unroll
      for (int mi = 0; mi < 4; mi++) {
        int row = wm * 64 + mi * 16 + c;
        af[mi] = *(const short8*)(smem + row * 128 + (((ks * 4 + g) ^ (row & 7)) * 16));
      }
#pragma unroll
      for (int ni = 0; ni < 4; ni++) {
        int row = wn * 64 + ni * 16 + c;
        bf[ni] = *(const short8*)(smem + 16384 + row * 128 + (((ks * 4 + g) ^ (row & 7)) * 16));
      }
#pragma unroll
      for (int mi = 0; mi < 4; mi++)
#pragma unroll
        for (int ni = 0; ni < 4; ni++)
          acc[mi][ni] = __builtin_amdgcn_mfma_f32_16x16x32_bf16(af[mi], bf[ni], acc[mi][ni], 0, 0, 0);
    }
  }

  // epilogue — C/D layout: col = lane&15, row = (lane>>4)*4 + reg
  const int cls = nt >> 1;                  // 0=q 1=k 2=v (block-uniform)
  const int cw = (nt & 1) * 128 + wn * 64;  // col base within 256-wide matrix
  const int rowbase = mt * 128 + wm * 64;
  if (cls == 0) {
#pragma unroll
    for (int ni = 0; ni < 4; ni++) {
      int col = cw + ni * 16 + c;
      float bias = bq[col];
#pragma unroll
      for (int mi = 0; mi < 4; mi++)
#pragma unroll
        for (int j = 0; j < 4; j++) {
          int row = rowbase + mi * 16 + g * 4 + j;
          qb[row * 256 + col] = f2bf((acc[mi][ni][j] + bias) * 0.044194173824159216f);
        }
    }
  } else if (cls == 1) {
#pragma unroll
    for (int ni = 0; ni < 4; ni++) {
      int col = cw + ni * 16 + c;
      float bias = bk[col];
#pragma unroll
      for (int mi = 0; mi < 4; mi++)
#pragma unroll
        for (int j = 0; j < 4; j++) {
          int row = rowbase + mi * 16 + g * 4 + j;
          kb[row * 256 + col] = f2bf(acc[mi][ni][j] + bias);
        }
    }
  } else {
    // v: per-wave 64(s) x 64(d) transpose through LDS, then coalesced stores
    __syncthreads();
    char* tb = smem + w * 8192;
#pragma unroll
    for (int ni = 0; ni < 4; ni++) {
      int dl = ni * 16 + c;
      float bias = bv[cw + dl];
#pragma unroll
      for (int mi = 0; mi < 4; mi++)
#pragma unroll
        for (int j = 0; j < 4; j++) {
          int sl = mi * 16 + g * 4 + j;
          *(short*)(tb + dl * 128 + ((sl * 2) ^ ((dl & 7) << 4))) =
              f2bf(acc[mi][ni][j] + bias);
        }
    }
    const int bb = rowbase >> 10, sb = rowbase & 1023;
#pragma unroll
    for (int i = 0; i < 8; i++) {
      int dl = i * 8 + (lane >> 3);
      int ch = lane & 7;
      short8 val = *(const short8*)(tb + dl * 128 + ((ch ^ (dl & 7)) * 16));
      *(short8*)(vt + (bb * 256 + cw + dl) * 1024 + sb + ch * 8) = val;
    }
  }
}

// ---------------- flash attention ----------------
// grid 256 = 16 b x 16 q-tiles(64 rows); 512 thr = 8 waves = 2 grps x 4 waves.
// grp 0: keys 0..511, grp 1: keys 512..1023; wave lw owns q-rows lw*16..+15.
// K: LDS double-buffered 64-key tiles (prefetch under compute, 1 barrier/iter).
// V: direct L2->reg loads (no staging). 8 kt iters; end: 2-way LDS merge.
// LDS: K[2 grp][2 buf][32K] = 128K | P 8x2304 | ml 512 = 150016 B.
__global__ __launch_bounds__(512, 2) void attn_kernel(
    const short* __restrict__ qb, const short* __restrict__ kb,
    const short* __restrict__ vt, float* __restrict__ out) {
  __shared__ __align__(16) char smem[150016];
  const int bid = blockIdx.x;
  const int swz = (bid & 7) * 32 + (bid >> 3);  // 2 batches per XCD chunk
  const int b = swz >> 4, qt = swz & 15;
  const int tid = threadIdx.x;
  const int w = tid >> 6, lane = tid & 63;
  const int grp = w >> 2, lw = w & 3;
  const int g = lane >> 4, c = lane & 15;
  const int q0 = b * 1024 + qt * 64 + lw * 16;
  short* sp = (short*)(smem + 131072 + w * 2304);  // per-wave P [16][72]
  const int krow0 = b * 1024 + grp * 512;
  const short* vrow = vt + (size_t)(b * 256) * 1024 + grp * 512;  // + d*1024 + s

  // Q in registers (A-frags, 8 k-steps of 32 dims) — same rows both grps
  short8 qf[8];
#pragma unroll
  for (int ks = 0; ks < 8; ks++)
    qf[ks] = *(const short8*)(qb + (q0 + c) * 256 + ks * 32 + g * 8);

  f32x4 O[16];
  const f32x4 fzero = {0.f, 0.f, 0.f, 0.f};
#pragma unroll
  for (int ni = 0; ni < 16; ni++) O[ni] = fzero;
  float m_[4] = {-1e30f, -1e30f, -1e30f, -1e30f};
  float l_[4] = {0.f, 0.f, 0.f, 0.f};

  // stage one 64-key K tile (32 KB per grp, 8 glls per wave)
  auto stageK = [&](int kt, int buf) {
    char* dst = smem + (grp * 2 + buf) * 32768;
#pragma unroll
    for (int i = 0; i < 8; i++) {
      int j = lw * 8 + i;                // 0..31, 2 rows per gll
      int r = j * 2 + (lane >> 5);
      int cc = lane & 31;
      GLL16(kb + (krow0 + kt * 64 + r) * 256 + ((cc ^ (r & 7)) * 8),
            dst + j * 1024);
    }
  };

  stageK(0, 0);
  for (int kt = 0; kt < 8; ++kt) {
    const int cur = kt & 1;
    const char* kbase = smem + (grp * 2 + cur) * 32768;
    asm volatile("s_waitcnt vmcnt(0)" ::: "memory");
    __syncthreads();
    if (kt < 7) stageK(kt + 1, cur ^ 1);  // prefetch flies under compute

    // QK^T: S[16 rows x 64 keys] per wave
    f32x4 Sf[4];
#pragma unroll
    for (int nf = 0; nf < 4; nf++) Sf[nf] = fzero;
#pragma unroll
    for (int ks = 0; ks < 8; ks++) {
      short8 kf[4];
#pragma unroll
      for (int nf = 0; nf < 4; nf++) {
        int key = nf * 16 + c;
        kf[nf] = *(const short8*)(kbase + key * 512 + (((ks * 4 + g) ^ (c & 7)) * 16));
      }
#pragma unroll
      for (int nf = 0; nf < 4; nf++)
        Sf[nf] = __builtin_amdgcn_mfma_f32_16x16x32_bf16(qf[ks], kf[nf], Sf[nf], 0, 0, 0);
    }

    // V first-half loads (keys kt*64 .. +31) — L2 latency hides under softmax
    short8 vfA[16];
#pragma unroll
    for (int ni = 0; ni < 16; ni++)
      vfA[ni] = *(const short8*)(vrow + (size_t)(ni * 16 + c) * 1024 + kt * 64 + g * 8);

    // online softmax with defer-max; lane holds rows 4g+j, keys c+16*nf
    float tm[4];
#pragma unroll
    for (int j = 0; j < 4; j++) {
      float t = fmaxf(fmaxf(Sf[0][j], Sf[1][j]), fmaxf(Sf[2][j], Sf[3][j]));
      t = fmaxf(t, __shfl_xor(t, 1));
      t = fmaxf(t, __shfl_xor(t, 2));
      t = fmaxf(t, __shfl_xor(t, 4));
      t = fmaxf(t, __shfl_xor(t, 8));
      tm[j] = t;
    }
    bool need = (tm[0] > m_[0] + 8.f) || (tm[1] > m_[1] + 8.f) ||
                (tm[2] > m_[2] + 8.f) || (tm[3] > m_[3] + 8.f);
    float Pv[4][4];
    if (__any(need)) {
      float scl[4];
#pragma unroll
      for (int j = 0; j < 4; j++) {
        float nm = fmaxf(m_[j], tm[j]);
        scl[j] = __expf(m_[j] - nm);
        m_[j] = nm;
        float rs = 0.f;
#pragma unroll
        for (int nf = 0; nf < 4; nf++) {
          float p = __expf(Sf[nf][j] - nm);
          Pv[nf][j] = p;
          rs += p;
        }
        rs += __shfl_xor(rs, 1);
        rs += __shfl_xor(rs, 2);
        rs += __shfl_xor(rs, 4);
        rs += __shfl_xor(rs, 8);
        l_[j] = l_[j] * scl[j] + rs;
      }
#pragma unroll
      for (int ni = 0; ni < 16; ni++) {
        O[ni][0] *= scl[0]; O[ni][1] *= scl[1];
        O[ni][2] *= scl[2]; O[ni][3] *= scl[3];
      }
    } else {
      // defer: keep m_, no O rescale; P bounded by e^8 (exact algebra)
#pragma unroll
      for (int j = 0; j < 4; j++) {
        float rs = 0.f;
#pragma unroll
        for (int nf = 0; nf < 4; nf++) {
          float p = __expf(Sf[nf][j] - m_[j]);
          Pv[nf][j] = p;
          rs += p;
        }
        rs += __shfl_xor(rs, 1);
        rs += __shfl_xor(rs, 2);
        rs += __shfl_xor(rs, 4);
        rs += __shfl_xor(rs, 8);
        l_[j] += rs;
      }
    }

    // P (bf16) -> per-wave LDS [16][72] -> A-frags (same wave, lgkm only)
#pragma unroll
    for (int nf = 0; nf < 4; nf++)
#pragma unroll
      for (int j = 0; j < 4; j++)
        sp[(g * 4 + j) * 72 + nf * 16 + c] = f2bf(Pv[nf][j]);

    short8 pf[2];
#pragma unroll
    for (int ks2 = 0; ks2 < 2; ks2++)
      pf[ks2] = *(const short8*)((char*)sp + c * 144 + ks2 * 64 + g * 16);

    // PV half A (keys +0..31) from regs
#pragma unroll
    for (int ni = 0; ni < 16; ni++)
      O[ni] = __builtin_amdgcn_mfma_f32_16x16x32_bf16(pf[0], vfA[ni], O[ni], 0, 0, 0);
    // V second-half loads (keys +32..63), then PV half B
    short8 vfB[16];
#pragma unroll
    for (int ni = 0; ni < 16; ni++)
      vfB[ni] = *(const short8*)(vrow + (size_t)(ni * 16 + c) * 1024 + kt * 64 + 32 + g * 8);
#pragma unroll
    for (int ni = 0; ni < 16; ni++)
      O[ni] = __builtin_amdgcn_mfma_f32_16x16x32_bf16(pf[1], vfB[ni], O[ni], 0, 0, 0);
  }

  // ---- 2-way merge through LDS (reuse K region; 80B row pitch) ----
  __syncthreads();  // all waves done with K LDS
  float2* mlb = (float2*)(smem + 149504);
  if (grp == 1) {
    char* ob = smem + lw * 20480;  // [256 d][16 rows + pad]
#pragma unroll
    for (int ni = 0; ni < 16; ni++)
      *(f32x4*)(ob + (ni * 16 + c) * 80 + g * 16) = O[ni];
#pragma unroll
    for (int j = 0; j < 4; j++) {
      float2 ml; ml.x = m_[j]; ml.y = l_[j];
      mlb[lw * 16 + g * 4 + j] = ml;
    }
  }
  __syncthreads();
  if (grp == 0) {
    char* ob = smem + lw * 20480;
    float a1[4], a2[4], inv[4];
#pragma unroll
    for (int j = 0; j < 4; j++) {
      float2 ml2 = mlb[lw * 16 + g * 4 + j];
      float mm = fmaxf(m_[j], ml2.x);
      a1[j] = __expf(m_[j] - mm);
      a2[j] = __expf(ml2.x - mm);
      inv[j] = 1.0f / (a1[j] * l_[j] + a2[j] * ml2.y);
    }
#pragma unroll
    for (int ni = 0; ni < 16; ni++) {
      f32x4 o2 = *(const f32x4*)(ob + (ni * 16 + c) * 80 + g * 16);
#pragma unroll
      for (int j = 0; j < 4; j++) {
        int row = q0 + g * 4 + j;
        out[row * 256 + ni * 16 + c] = (a1[j] * O[ni][j] + a2[j] * o2[j]) * inv[j];
      }
    }
  }
}

extern "C" void kernel_launch(void* const* d_in, const int* in_sizes, int n_in,
                              void* d_out, int out_size, void* d_ws, size_t ws_size,
                              hipStream_t stream) {
  const float* x  = (const float*)d_in[0];
  const float* wq = (const float*)d_in[1];
  const float* bq = (const float*)d_in[2];
  const float* wk = (const float*)d_in[3];
  const float* bk = (const float*)d_in[4];
  const float* wv = (const float*)d_in[5];
  const float* bv = (const float*)d_in[6];
  float* out = (float*)d_out;
  char* ws = (char*)d_ws;
  // ws layout (bytes): qb 8,388,608 | kb 8,388,608 | vt 8,388,608
  short* qb = (short*)ws;
  short* kb = (short*)(ws + 8388608);
  short* vt = (short*)(ws + 16777216);

  qkv_gemm<<<768, 256, 0, stream>>>(x, wq, wk, wv, bq, bk, bv, qb, kb, vt);
  attn_kernel<<<256, 512, 0, stream>>>(qb, kb, vt, out);
}

// Round 8
// 159.754 us; speedup vs baseline: 2.3912x; 1.8406x over previous
//
#include <hip/hip_runtime.h>
#include <hip/hip_bf16.h>

// Problem: B=16, S=1024, IN=512, OUT=256.
// out = softmax((x@wq^T + bq)(x@wk^T + bk)^T / sqrt(512)) @ (x@wv^T + bv)
// RoPE cancels (same rotation applied to q and k) -> skipped.
// qkv_gemm: fp32 in, inline bf16 cvt, T14 prefetch (unchanged, passing).
// attn: 2-way in-block split-K flash, 512 thr; K AND V double-buffered in
// LDS with 32-key tiles (1 barrier/iter, prefetch under compute).
// Register budget rule (rounds 6/7 lesson): O(64)+qf(32)+<=32 transient;
// no V-in-reg arrays, no min-waves arg to __launch_bounds__.

typedef __attribute__((ext_vector_type(8))) short short8;
typedef __attribute__((ext_vector_type(4))) short short4v;
typedef __attribute__((ext_vector_type(4))) float f32x4;

#define GLL16(g, l)                                                            \
  __builtin_amdgcn_global_load_lds(                                            \
      (const __attribute__((address_space(1))) unsigned int*)(g),              \
      (__attribute__((address_space(3))) unsigned int*)(l), 16, 0, 0)

static __device__ __forceinline__ short f2bf(float f) {
  __hip_bfloat16 h = __float2bfloat16(f);
  return __builtin_bit_cast(short, h);
}

// ---------------- QKV GEMM (unchanged from round 4; passed) ----------------
__global__ __launch_bounds__(256) void qkv_gemm(
    const float* __restrict__ x, const float* __restrict__ wq,
    const float* __restrict__ wk, const float* __restrict__ wv,
    const float* __restrict__ bq, const float* __restrict__ bk,
    const float* __restrict__ bv, short* __restrict__ qb,
    short* __restrict__ kb, short* __restrict__ vt) {
  __shared__ __align__(16) char smem[32768];
  const int bid = blockIdx.x;                   // 768 blocks
  const int swz = (bid & 7) * 96 + (bid >> 3);  // XCD chunking (768 % 8 == 0)
  const int mt = swz / 6, nt = swz % 6;
  const int tid = threadIdx.x;
  const int w = tid >> 6, lane = tid & 63;
  const int g = lane >> 4, c = lane & 15;
  const int wm = w >> 1, wn = w & 1;

  const float* wsel = (nt < 2) ? wq : (nt < 4) ? wk : wv;
  const int wro = (nt & 1) * 128;

  f32x4 acc[4][4];
  const f32x4 fzero = {0.f, 0.f, 0.f, 0.f};
#pragma unroll
  for (int mi = 0; mi < 4; mi++)
#pragma unroll
    for (int ni = 0; ni < 4; ni++) acc[mi][ni] = fzero;

  const int arow = tid >> 4;   // 0..15
  const int acol4 = tid & 15;  // float4 index within 64-wide k slice
  const int achunk = acol4 >> 1, ahalf = (tid & 1) * 8;

  float4 xv[8], wv8[8];
#pragma unroll
  for (int j = 0; j < 8; j++) {  // prologue load kk=0
    int row = j * 16 + arow;
    xv[j] = *(const float4*)(x + (mt * 128 + row) * 512 + acol4 * 4);
    wv8[j] = *(const float4*)(wsel + (wro + row) * 512 + acol4 * 4);
  }

  for (int kk = 0; kk < 8; ++kk) {
    __syncthreads();
#pragma unroll
    for (int j = 0; j < 8; j++) {
      int row = j * 16 + arow;
      short4v s4;
      s4[0] = f2bf(xv[j].x); s4[1] = f2bf(xv[j].y);
      s4[2] = f2bf(xv[j].z); s4[3] = f2bf(xv[j].w);
      *(short4v*)(smem + row * 128 + ((achunk ^ (row & 7)) * 16) + ahalf) = s4;
      short4v t4;
      t4[0] = f2bf(wv8[j].x); t4[1] = f2bf(wv8[j].y);
      t4[2] = f2bf(wv8[j].z); t4[3] = f2bf(wv8[j].w);
      *(short4v*)(smem + 16384 + row * 128 + ((achunk ^ (row & 7)) * 16) + ahalf) = t4;
    }
    __syncthreads();
    if (kk < 7) {  // issue next tile's loads; latency hides under MFMA below
#pragma unroll
      for (int j = 0; j < 8; j++) {
        int row = j * 16 + arow;
        xv[j] = *(const float4*)(x + (mt * 128 + row) * 512 + (kk + 1) * 64 + acol4 * 4);
        wv8[j] = *(const float4*)(wsel + (wro + row) * 512 + (kk + 1) * 64 + acol4 * 4);
      }
    }
#pragma unroll
    for (int ks = 0; ks < 2; ++ks) {
      short8 af[4], bf[4];
#pragma unroll
      for (int mi = 0; mi < 4; mi++) {
        int row = wm * 64 + mi * 16 + c;
        af[mi] = *(const short8*)(smem + row * 128 + (((ks * 4 + g) ^ (row & 7)) * 16));
      }
#pragma unroll
      for (int ni = 0; ni < 4; ni++) {
        int row = wn * 64 + ni * 16 + c;
        bf[ni] = *(const short8*)(smem + 16384 + row * 128 + (((ks * 4 + g) ^ (row & 7)) * 16));
      }
#pragma unroll
      for (int mi = 0; mi < 4; mi++)
#pragma unroll
        for (int ni = 0; ni < 4; ni++)
          acc[mi][ni] = __builtin_amdgcn_mfma_f32_16x16x32_bf16(af[mi], bf[ni], acc[mi][ni], 0, 0, 0);
    }
  }

  // epilogue — C/D layout: col = lane&15, row = (lane>>4)*4 + reg
  const int cls = nt >> 1;                  // 0=q 1=k 2=v (block-uniform)
  const int cw = (nt & 1) * 128 + wn * 64;  // col base within 256-wide matrix
  const int rowbase = mt * 128 + wm * 64;
  if (cls == 0) {
#pragma unroll
    for (int ni = 0; ni < 4; ni++) {
      int col = cw + ni * 16 + c;
      float bias = bq[col];
#pragma unroll
      for (int mi = 0; mi < 4; mi++)
#pragma unroll
        for (int j = 0; j < 4; j++) {
          int row = rowbase + mi * 16 + g * 4 + j;
          qb[row * 256 + col] = f2bf((acc[mi][ni][j] + bias) * 0.044194173824159216f);
        }
    }
  } else if (cls == 1) {
#pragma unroll
    for (int ni = 0; ni < 4; ni++) {
      int col = cw + ni * 16 + c;
      float bias = bk[col];
#pragma unroll
      for (int mi = 0; mi < 4; mi++)
#pragma unroll
        for (int j = 0; j < 4; j++) {
          int row = rowbase + mi * 16 + g * 4 + j;
          kb[row * 256 + col] = f2bf(acc[mi][ni][j] + bias);
        }
    }
  } else {
    // v: per-wave 64(s) x 64(d) transpose through LDS, then coalesced stores
    __syncthreads();
    char* tb = smem + w * 8192;
#pragma unroll
    for (int ni = 0; ni < 4; ni++) {
      int dl = ni * 16 + c;
      float bias = bv[cw + dl];
#pragma unroll
      for (int mi = 0; mi < 4; mi++)
#pragma unroll
        for (int j = 0; j < 4; j++) {
          int sl = mi * 16 + g * 4 + j;
          *(short*)(tb + dl * 128 + ((sl * 2) ^ ((dl & 7) << 4))) =
              f2bf(acc[mi][ni][j] + bias);
        }
    }
    const int bb = rowbase >> 10, sb = rowbase & 1023;
#pragma unroll
    for (int i = 0; i < 8; i++) {
      int dl = i * 8 + (lane >> 3);
      int ch = lane & 7;
      short8 val = *(const short8*)(tb + dl * 128 + ((ch ^ (dl & 7)) * 16));
      *(short8*)(vt + (bb * 256 + cw + dl) * 1024 + sb + ch * 8) = val;
    }
  }
}

// ---------------- flash attention ----------------
// grid 256 = 16 b x 16 q-tiles(64 rows); 512 thr = 8 waves = 2 grps x 4 waves.
// grp 0: keys 0..511, grp 1: keys 512..1023; wave lw owns q-rows lw*16..+15.
// 32-key tiles, 16 iters; K and V double-buffered in LDS; per iter:
// vmcnt(0) -> barrier -> issue next tile glls (fly under compute) -> compute.
// LDS per grp: K[2][16K] @ grp*32K | V[2][16K] @ 64K+grp*32K.
// P: 128K + w*1280 ([16][40] bf16). ml @ 141312. Total 141824 B.
__global__ __launch_bounds__(512) void attn_kernel(
    const short* __restrict__ qb, const short* __restrict__ kb,
    const short* __restrict__ vt, float* __restrict__ out) {
  __shared__ __align__(16) char smem[141824];
  const int bid = blockIdx.x;
  const int swz = (bid & 7) * 32 + (bid >> 3);  // 2 batches per XCD chunk
  const int b = swz >> 4, qt = swz & 15;
  const int tid = threadIdx.x;
  const int w = tid >> 6, lane = tid & 63;
  const int grp = w >> 2, lw = w & 3;
  const int g = lane >> 4, c = lane & 15;
  const int q0 = b * 1024 + qt * 64 + lw * 16;
  short* sp = (short*)(smem + 131072 + w * 1280);  // per-wave P [16][40]
  const int krow0 = b * 1024 + grp * 512;

  // Q in registers (A-frags, 8 k-steps of 32 dims) — same rows both grps
  short8 qf[8];
#pragma unroll
  for (int ks = 0; ks < 8; ks++)
    qf[ks] = *(const short8*)(qb + (q0 + c) * 256 + ks * 32 + g * 8);

  f32x4 O[16];
  const f32x4 fzero = {0.f, 0.f, 0.f, 0.f};
#pragma unroll
  for (int ni = 0; ni < 16; ni++) O[ni] = fzero;
  float m_[4] = {-1e30f, -1e30f, -1e30f, -1e30f};
  float l_[4] = {0.f, 0.f, 0.f, 0.f};

  // stage one 32-key K+V tile pair into buffer buf (8 glls per wave)
  auto stage = [&](int kt, int buf) {
    char* kdst = smem + grp * 32768 + buf * 16384;          // [32 keys][512B]
    char* vdst = smem + 65536 + grp * 32768 + buf * 16384;  // [256 d][64B]
#pragma unroll
    for (int i = 0; i < 4; i++) {
      int j = lw * 4 + i;                 // 0..15, 2 key-rows per gll
      int r = j * 2 + (lane >> 5);
      int cc = lane & 31;
      GLL16(kb + (krow0 + kt * 32 + r) * 256 + ((cc ^ (r & 7)) * 8),
            kdst + j * 1024);
    }
#pragma unroll
    for (int i = 0; i < 4; i++) {
      int j = lw * 4 + i;                 // 0..15, 16 d-rows per gll
      int r = j * 16 + (lane >> 2);
      int cc = lane & 3;
      GLL16(vt + (b * 256 + r) * 1024 + grp * 512 + kt * 32 + ((cc ^ (r & 3)) * 8),
            vdst + j * 1024);
    }
  };

  stage(0, 0);
  for (int kt = 0; kt < 16; ++kt) {
    const int cur = kt & 1;
    const char* kbase = smem + grp * 32768 + cur * 16384;
    const char* vbase = smem + 65536 + grp * 32768 + cur * 16384;
    asm volatile("s_waitcnt vmcnt(0)" ::: "memory");
    __syncthreads();
    if (kt < 15) stage(kt + 1, cur ^ 1);  // prefetch flies under compute

    // QK^T: S[16 rows x 32 keys] per wave (16 MFMA)
    f32x4 Sf[2];
    Sf[0] = fzero; Sf[1] = fzero;
#pragma unroll
    for (int ks = 0; ks < 8; ks++) {
      short8 kf[2];
#pragma unroll
      for (int nf = 0; nf < 2; nf++) {
        int key = nf * 16 + c;
        kf[nf] = *(const short8*)(kbase + key * 512 + (((ks * 4 + g) ^ (c & 7)) * 16));
      }
#pragma unroll
      for (int nf = 0; nf < 2; nf++)
        Sf[nf] = __builtin_amdgcn_mfma_f32_16x16x32_bf16(qf[ks], kf[nf], Sf[nf], 0, 0, 0);
    }

    // online softmax with defer-max; lane holds rows 4g+j, keys c and c+16
    float tm[4];
#pragma unroll
    for (int j = 0; j < 4; j++) {
      float t = fmaxf(Sf[0][j], Sf[1][j]);
      t = fmaxf(t, __shfl_xor(t, 1));
      t = fmaxf(t, __shfl_xor(t, 2));
      t = fmaxf(t, __shfl_xor(t, 4));
      t = fmaxf(t, __shfl_xor(t, 8));
      tm[j] = t;
    }
    bool need = (tm[0] > m_[0] + 8.f) || (tm[1] > m_[1] + 8.f) ||
                (tm[2] > m_[2] + 8.f) || (tm[3] > m_[3] + 8.f);
    float Pv[2][4];
    if (__any(need)) {
      float scl[4];
#pragma unroll
      for (int j = 0; j < 4; j++) {
        float nm = fmaxf(m_[j], tm[j]);
        scl[j] = __expf(m_[j] - nm);
        m_[j] = nm;
        float rs = 0.f;
#pragma unroll
        for (int nf = 0; nf < 2; nf++) {
          float p = __expf(Sf[nf][j] - nm);
          Pv[nf][j] = p;
          rs += p;
        }
        rs += __shfl_xor(rs, 1);
        rs += __shfl_xor(rs, 2);
        rs += __shfl_xor(rs, 4);
        rs += __shfl_xor(rs, 8);
        l_[j] = l_[j] * scl[j] + rs;
      }
#pragma unroll
      for (int ni = 0; ni < 16; ni++) {
        O[ni][0] *= scl[0]; O[ni][1] *= scl[1];
        O[ni][2] *= scl[2]; O[ni][3] *= scl[3];
      }
    } else {
      // defer: keep m_, no O rescale; P bounded by e^8 (exact algebra)
#pragma unroll
      for (int j = 0; j < 4; j++) {
        float rs = 0.f;
#pragma unroll
        for (int nf = 0; nf < 2; nf++) {
          float p = __expf(Sf[nf][j] - m_[j]);
          Pv[nf][j] = p;
          rs += p;
        }
        rs += __shfl_xor(rs, 1);
        rs += __shfl_xor(rs, 2);
        rs += __shfl_xor(rs, 4);
        rs += __shfl_xor(rs, 8);
        l_[j] += rs;
      }
    }

    // P (bf16) -> per-wave LDS [16][40] -> A-frag (same wave, lgkm only)
#pragma unroll
    for (int nf = 0; nf < 2; nf++)
#pragma unroll
      for (int j = 0; j < 4; j++)
        sp[(g * 4 + j) * 40 + nf * 16 + c] = f2bf(Pv[nf][j]);

    short8 pf = *(const short8*)((char*)sp + c * 80 + g * 16);

    // PV: O[16 rows x 256 d] += P[16x32] @ V[32x256] (16 MFMA)
#pragma unroll
    for (int ni = 0; ni < 16; ni++) {
      int d = ni * 16 + c;
      short8 vf = *(const short8*)(vbase + d * 64 + ((g ^ (d & 3)) * 16));
      O[ni] = __builtin_amdgcn_mfma_f32_16x16x32_bf16(pf, vf, O[ni], 0, 0, 0);
    }
  }

  // ---- 2-way merge through LDS (reuse K/V region; 80B row pitch) ----
  __syncthreads();  // all waves done with K/V LDS
  float2* mlb = (float2*)(smem + 141312);
  if (grp == 1) {
    char* ob = smem + lw * 20480;  // [256 d][16 rows + pad]
#pragma unroll
    for (int ni = 0; ni < 16; ni++)
      *(f32x4*)(ob + (ni * 16 + c) * 80 + g * 16) = O[ni];
#pragma unroll
    for (int j = 0; j < 4; j++) {
      float2 ml; ml.x = m_[j]; ml.y = l_[j];
      mlb[lw * 16 + g * 4 + j] = ml;
    }
  }
  __syncthreads();
  if (grp == 0) {
    char* ob = smem + lw * 20480;
    float a1[4], a2[4], inv[4];
#pragma unroll
    for (int j = 0; j < 4; j++) {
      float2 ml2 = mlb[lw * 16 + g * 4 + j];
      float mm = fmaxf(m_[j], ml2.x);
      a1[j] = __expf(m_[j] - mm);
      a2[j] = __expf(ml2.x - mm);
      inv[j] = 1.0f / (a1[j] * l_[j] + a2[j] * ml2.y);
    }
#pragma unroll
    for (int ni = 0; ni < 16; ni++) {
      f32x4 o2 = *(const f32x4*)(ob + (ni * 16 + c) * 80 + g * 16);
#pragma unroll
      for (int j = 0; j < 4; j++) {
        int row = q0 + g * 4 + j;
        out[row * 256 + ni * 16 + c] = (a1[j] * O[ni][j] + a2[j] * o2[j]) * inv[j];
      }
    }
  }
}

extern "C" void kernel_launch(void* const* d_in, const int* in_sizes, int n_in,
                              void* d_out, int out_size, void* d_ws, size_t ws_size,
                              hipStream_t stream) {
  const float* x  = (const float*)d_in[0];
  const float* wq = (const float*)d_in[1];
  const float* bq = (const float*)d_in[2];
  const float* wk = (const float*)d_in[3];
  const float* bk = (const float*)d_in[4];
  const float* wv = (const float*)d_in[5];
  const float* bv = (const float*)d_in[6];
  float* out = (float*)d_out;
  char* ws = (char*)d_ws;
  // ws layout (bytes): qb 8,388,608 | kb 8,388,608 | vt 8,388,608
  short* qb = (short*)ws;
  short* kb = (short*)(ws + 8388608);
  short* vt = (short*)(ws + 16777216);

  qkv_gemm<<<768, 256, 0, stream>>>(x, wq, wk, wv, bq, bk, bv, qb, kb, vt);
  attn_kernel<<<256, 512, 0, stream>>>(qb, kb, vt, out);
}

// Round 9
// 155.121 us; speedup vs baseline: 2.4626x; 1.0299x over previous
//
#include <hip/hip_runtime.h>
#include <hip/hip_bf16.h>

// Problem: B=16, S=1024, IN=512, OUT=256.
// out = softmax((x@wq^T + bq)(x@wk^T + bk)^T / sqrt(512)) @ (x@wv^T + bv)
// RoPE cancels (same rotation applied to q and k) -> skipped.
// qkv_gemm: fp32 in, inline bf16 cvt, T14 prefetch (frozen from round 4).
// attn: 2-way in-block split-K flash, 512 thr, SWAPPED-OPERAND mfma
// (S^T = K x Q, O^T = V x P) so softmax is per-lane scalar (qrow = lane&15);
// V reg-staged into 80B-pitch LDS (kills 4-way bank conflict); K dbuf gll.

typedef __attribute__((ext_vector_type(8))) short short8;
typedef __attribute__((ext_vector_type(4))) short short4v;
typedef __attribute__((ext_vector_type(4))) float f32x4;

#define GLL16(g, l)                                                            \
  __builtin_amdgcn_global_load_lds(                                            \
      (const __attribute__((address_space(1))) unsigned int*)(g),              \
      (__attribute__((address_space(3))) unsigned int*)(l), 16, 0, 0)

static __device__ __forceinline__ short f2bf(float f) {
  __hip_bfloat16 h = __float2bfloat16(f);
  return __builtin_bit_cast(short, h);
}

// ---------------- QKV GEMM (unchanged from round 4; passed) ----------------
__global__ __launch_bounds__(256) void qkv_gemm(
    const float* __restrict__ x, const float* __restrict__ wq,
    const float* __restrict__ wk, const float* __restrict__ wv,
    const float* __restrict__ bq, const float* __restrict__ bk,
    const float* __restrict__ bv, short* __restrict__ qb,
    short* __restrict__ kb, short* __restrict__ vt) {
  __shared__ __align__(16) char smem[32768];
  const int bid = blockIdx.x;                   // 768 blocks
  const int swz = (bid & 7) * 96 + (bid >> 3);  // XCD chunking (768 % 8 == 0)
  const int mt = swz / 6, nt = swz % 6;
  const int tid = threadIdx.x;
  const int w = tid >> 6, lane = tid & 63;
  const int g = lane >> 4, c = lane & 15;
  const int wm = w >> 1, wn = w & 1;

  const float* wsel = (nt < 2) ? wq : (nt < 4) ? wk : wv;
  const int wro = (nt & 1) * 128;

  f32x4 acc[4][4];
  const f32x4 fzero = {0.f, 0.f, 0.f, 0.f};
#pragma unroll
  for (int mi = 0; mi < 4; mi++)
#pragma unroll
    for (int ni = 0; ni < 4; ni++) acc[mi][ni] = fzero;

  const int arow = tid >> 4;   // 0..15
  const int acol4 = tid & 15;  // float4 index within 64-wide k slice
  const int achunk = acol4 >> 1, ahalf = (tid & 1) * 8;

  float4 xv[8], wv8[8];
#pragma unroll
  for (int j = 0; j < 8; j++) {  // prologue load kk=0
    int row = j * 16 + arow;
    xv[j] = *(const float4*)(x + (mt * 128 + row) * 512 + acol4 * 4);
    wv8[j] = *(const float4*)(wsel + (wro + row) * 512 + acol4 * 4);
  }

  for (int kk = 0; kk < 8; ++kk) {
    __syncthreads();
#pragma unroll
    for (int j = 0; j < 8; j++) {
      int row = j * 16 + arow;
      short4v s4;
      s4[0] = f2bf(xv[j].x); s4[1] = f2bf(xv[j].y);
      s4[2] = f2bf(xv[j].z); s4[3] = f2bf(xv[j].w);
      *(short4v*)(smem + row * 128 + ((achunk ^ (row & 7)) * 16) + ahalf) = s4;
      short4v t4;
      t4[0] = f2bf(wv8[j].x); t4[1] = f2bf(wv8[j].y);
      t4[2] = f2bf(wv8[j].z); t4[3] = f2bf(wv8[j].w);
      *(short4v*)(smem + 16384 + row * 128 + ((achunk ^ (row & 7)) * 16) + ahalf) = t4;
    }
    __syncthreads();
    if (kk < 7) {
#pragma unroll
      for (int j = 0; j < 8; j++) {
        int row = j * 16 + arow;
        xv[j] = *(const float4*)(x + (mt * 128 + row) * 512 + (kk + 1) * 64 + acol4 * 4);
        wv8[j] = *(const float4*)(wsel + (wro + row) * 512 + (kk + 1) * 64 + acol4 * 4);
      }
    }
#pragma unroll
    for (int ks = 0; ks < 2; ++ks) {
      short8 af[4], bf[4];
#pragma unroll
      for (int mi = 0; mi < 4; mi++) {
        int row = wm * 64 + mi * 16 + c;
        af[mi] = *(const short8*)(smem + row * 128 + (((ks * 4 + g) ^ (row & 7)) * 16));
      }
#pragma unroll
      for (int ni = 0; ni < 4; ni++) {
        int row = wn * 64 + ni * 16 + c;
        bf[ni] = *(const short8*)(smem + 16384 + row * 128 + (((ks * 4 + g) ^ (row & 7)) * 16));
      }
#pragma unroll
      for (int mi = 0; mi < 4; mi++)
#pragma unroll
        for (int ni = 0; ni < 4; ni++)
          acc[mi][ni] = __builtin_amdgcn_mfma_f32_16x16x32_bf16(af[mi], bf[ni], acc[mi][ni], 0, 0, 0);
    }
  }

  const int cls = nt >> 1;
  const int cw = (nt & 1) * 128 + wn * 64;
  const int rowbase = mt * 128 + wm * 64;
  if (cls == 0) {
#pragma unroll
    for (int ni = 0; ni < 4; ni++) {
      int col = cw + ni * 16 + c;
      float bias = bq[col];
#pragma unroll
      for (int mi = 0; mi < 4; mi++)
#pragma unroll
        for (int j = 0; j < 4; j++) {
          int row = rowbase + mi * 16 + g * 4 + j;
          qb[row * 256 + col] = f2bf((acc[mi][ni][j] + bias) * 0.044194173824159216f);
        }
    }
  } else if (cls == 1) {
#pragma unroll
    for (int ni = 0; ni < 4; ni++) {
      int col = cw + ni * 16 + c;
      float bias = bk[col];
#pragma unroll
      for (int mi = 0; mi < 4; mi++)
#pragma unroll
        for (int j = 0; j < 4; j++) {
          int row = rowbase + mi * 16 + g * 4 + j;
          kb[row * 256 + col] = f2bf(acc[mi][ni][j] + bias);
        }
    }
  } else {
    __syncthreads();
    char* tb = smem + w * 8192;
#pragma unroll
    for (int ni = 0; ni < 4; ni++) {
      int dl = ni * 16 + c;
      float bias = bv[cw + dl];
#pragma unroll
      for (int mi = 0; mi < 4; mi++)
#pragma unroll
        for (int j = 0; j < 4; j++) {
          int sl = mi * 16 + g * 4 + j;
          *(short*)(tb + dl * 128 + ((sl * 2) ^ ((dl & 7) << 4))) =
              f2bf(acc[mi][ni][j] + bias);
        }
    }
    const int bb = rowbase >> 10, sb = rowbase & 1023;
#pragma unroll
    for (int i = 0; i < 8; i++) {
      int dl = i * 8 + (lane >> 3);
      int ch = lane & 7;
      short8 val = *(const short8*)(tb + dl * 128 + ((ch ^ (dl & 7)) * 16));
      *(short8*)(vt + (bb * 256 + cw + dl) * 1024 + sb + ch * 8) = val;
    }
  }
}

// ---------------- flash attention, swapped-operand ----------------
// grid 256 = 16 b x 16 q-tiles(64 rows); 512 thr = 8 waves = 2 grps x 4 waves.
// grp: keys grp*512..+511; wave lw owns q-rows lw*16..+15 (qrow = lane&15).
// 32-key tiles, 16 iters. K: gll double-buffer [32][512B] chunk-XOR.
// V: global->reg prefetch, reg->LDS [256 d][80B pitch] (2-way banks only).
// S^T = mfma(K,Q): lane holds 8 S for ONE qrow -> scalar softmax, 4 shfl.
// O^T = mfma(V,P): qrow = lane&15, d = ni*16+g*4+j.
// LDS: K 2grp x 2buf x 16K = 64K | V 2grp x 20480 = 40K | P 8 x 1280 | ml.
__global__ __launch_bounds__(512) void attn_kernel(
    const short* __restrict__ qb, const short* __restrict__ kb,
    const short* __restrict__ vt, float* __restrict__ out) {
  __shared__ __align__(16) char smem[116992];
  const int bid = blockIdx.x;
  const int swz = (bid & 7) * 32 + (bid >> 3);  // 2 batches per XCD chunk
  const int b = swz >> 4, qt = swz & 15;
  const int tid = threadIdx.x;
  const int w = tid >> 6, lane = tid & 63;
  const int grp = w >> 2, lw = w & 3;
  const int g = lane >> 4, c = lane & 15;
  const int q0 = b * 1024 + qt * 64 + lw * 16;
  char* kbufs = smem + grp * 32768;
  char* vbase = smem + 65536 + grp * 20480;        // [256 d][80 B]
  short* sp = (short*)(smem + 106496 + w * 1280);  // P [16 qrow][40 keys]
  const int krow0 = b * 1024 + grp * 512;

  // Q fragments: B-operand, col = qrow = c (same for QK^T use)
  short8 qf[8];
#pragma unroll
  for (int ks = 0; ks < 8; ks++)
    qf[ks] = *(const short8*)(qb + (q0 + c) * 256 + ks * 32 + g * 8);

  f32x4 O[16];
  const f32x4 fzero = {0.f, 0.f, 0.f, 0.f};
#pragma unroll
  for (int ni = 0; ni < 16; ni++) O[ni] = fzero;
  float m_ = -1e30f, l_ = 0.f;  // per-lane scalars (qrow = c)

  const int vr = lane >> 2, vcc = lane & 3;  // V stage: row part, 16B chunk

  short8 vreg[4];
  auto loadV = [&](int kt) {
#pragma unroll
    for (int i = 0; i < 4; i++) {
      int d = lw * 64 + i * 16 + vr;
      vreg[i] = *(const short8*)(vt + (size_t)(b * 256 + d) * 1024 + grp * 512 +
                                 kt * 32 + vcc * 8);
    }
  };
  auto stageK = [&](int kt, int buf) {
    char* kdst = kbufs + buf * 16384;
#pragma unroll
    for (int i = 0; i < 4; i++) {
      int j = lw * 4 + i;
      int r = j * 2 + (lane >> 5);
      int cc = lane & 31;
      GLL16(kb + (krow0 + kt * 32 + r) * 256 + ((cc ^ (r & 7)) * 8),
            kdst + j * 1024);
    }
  };

  stageK(0, 0);
  loadV(0);
  for (int kt = 0; kt < 16; ++kt) {
    const int cur = kt & 1;
    const char* kbase = kbufs + cur * 16384;
    asm volatile("s_waitcnt vmcnt(0)" ::: "memory");  // K gll(kt) + V regs(kt)
    __syncthreads();  // everyone done reading prev V tile / this K buf is ready
    // V regs -> LDS, 80B pitch
#pragma unroll
    for (int i = 0; i < 4; i++) {
      int d = lw * 64 + i * 16 + vr;
      *(short8*)(vbase + d * 80 + vcc * 16) = vreg[i];
    }
    if (kt < 15) {  // prefetch next tile: K gll + V global->reg
      stageK(kt + 1, cur ^ 1);
      loadV(kt + 1);
    }
    __syncthreads();  // V writes visible

    // S^T = K x Q: lane holds S[key nf*16+g*4+j][qrow c]
    f32x4 Sf[2];
    Sf[0] = fzero; Sf[1] = fzero;
#pragma unroll
    for (int ks = 0; ks < 8; ks++) {
      short8 kf0 = *(const short8*)(kbase + c * 512 + (((ks * 4 + g) ^ (c & 7)) * 16));
      short8 kf1 = *(const short8*)(kbase + (16 + c) * 512 + (((ks * 4 + g) ^ (c & 7)) * 16));
      Sf[0] = __builtin_amdgcn_mfma_f32_16x16x32_bf16(kf0, qf[ks], Sf[0], 0, 0, 0);
      Sf[1] = __builtin_amdgcn_mfma_f32_16x16x32_bf16(kf1, qf[ks], Sf[1], 0, 0, 0);
    }

    // scalar softmax (qrow = c); reduce across g-groups only (2 shfl each)
    float tm = fmaxf(fmaxf(fmaxf(Sf[0][0], Sf[0][1]), fmaxf(Sf[0][2], Sf[0][3])),
                     fmaxf(fmaxf(Sf[1][0], Sf[1][1]), fmaxf(Sf[1][2], Sf[1][3])));
    tm = fmaxf(tm, __shfl_xor(tm, 16));
    tm = fmaxf(tm, __shfl_xor(tm, 32));
    float p[8];
    if (__any(tm > m_ + 8.f)) {
      float nm = fmaxf(m_, tm);
      float scl = __expf(m_ - nm);
      m_ = nm;
      float rs = 0.f;
#pragma unroll
      for (int i = 0; i < 4; i++) { p[i] = __expf(Sf[0][i] - nm); rs += p[i]; }
#pragma unroll
      for (int i = 0; i < 4; i++) { p[4 + i] = __expf(Sf[1][i] - nm); rs += p[4 + i]; }
      rs += __shfl_xor(rs, 16);
      rs += __shfl_xor(rs, 32);
      l_ = l_ * scl + rs;
#pragma unroll
      for (int ni = 0; ni < 16; ni++) {
        O[ni][0] *= scl; O[ni][1] *= scl; O[ni][2] *= scl; O[ni][3] *= scl;
      }
    } else {  // defer-max: exact (P bounded by e^8)
      float rs = 0.f;
#pragma unroll
      for (int i = 0; i < 4; i++) { p[i] = __expf(Sf[0][i] - m_); rs += p[i]; }
#pragma unroll
      for (int i = 0; i < 4; i++) { p[4 + i] = __expf(Sf[1][i] - m_); rs += p[4 + i]; }
      rs += __shfl_xor(rs, 16);
      rs += __shfl_xor(rs, 32);
      l_ += rs;
    }

    // P -> per-wave LDS [qrow][key] -> B-frag (lane needs keys g*8..+7)
    short4v pa, pb;
    pa[0] = f2bf(p[0]); pa[1] = f2bf(p[1]); pa[2] = f2bf(p[2]); pa[3] = f2bf(p[3]);
    pb[0] = f2bf(p[4]); pb[1] = f2bf(p[5]); pb[2] = f2bf(p[6]); pb[3] = f2bf(p[7]);
    *(short4v*)((char*)sp + c * 80 + g * 8) = pa;        // keys g*4+j
    *(short4v*)((char*)sp + c * 80 + 32 + g * 8) = pb;   // keys 16+g*4+j
    short8 pf = *(const short8*)((char*)sp + c * 80 + g * 16);

    // O^T += V x P: lane -> qrow c, d = ni*16+g*4+j
#pragma unroll
    for (int ni = 0; ni < 16; ni++) {
      int d = ni * 16 + c;
      short8 vf = *(const short8*)(vbase + d * 80 + g * 16);
      O[ni] = __builtin_amdgcn_mfma_f32_16x16x32_bf16(vf, pf, O[ni], 0, 0, 0);
    }
  }

  // ---- 2-way merge through LDS (reuse K/V region; pitch 1040 B) ----
  __syncthreads();
  float2* mlb = (float2*)(smem + 116736);
  if (grp == 1) {
    char* ob = smem + lw * 16640;  // [16 qrow][260 f32]
#pragma unroll
    for (int ni = 0; ni < 16; ni++)
      *(f32x4*)(ob + c * 1040 + (ni * 16 + g * 4) * 4) = O[ni];
    if (g == 0) { float2 ml; ml.x = m_; ml.y = l_; mlb[lw * 16 + c] = ml; }
  }
  __syncthreads();
  if (grp == 0) {
    char* ob = smem + lw * 16640;
    float2 ml2 = mlb[lw * 16 + c];
    float mm = fmaxf(m_, ml2.x);
    float a1 = __expf(m_ - mm), a2 = __expf(ml2.x - mm);
    float inv = 1.0f / (a1 * l_ + a2 * ml2.y);
#pragma unroll
    for (int ni = 0; ni < 16; ni++) {
      f32x4 o2 = *(const f32x4*)(ob + c * 1040 + (ni * 16 + g * 4) * 4);
      f32x4 r;
#pragma unroll
      for (int j = 0; j < 4; j++) r[j] = (a1 * O[ni][j] + a2 * o2[j]) * inv;
      *(f32x4*)(out + (q0 + c) * 256 + ni * 16 + g * 4) = r;
    }
  }
}

extern "C" void kernel_launch(void* const* d_in, const int* in_sizes, int n_in,
                              void* d_out, int out_size, void* d_ws, size_t ws_size,
                              hipStream_t stream) {
  const float* x  = (const float*)d_in[0];
  const float* wq = (const float*)d_in[1];
  const float* bq = (const float*)d_in[2];
  const float* wk = (const float*)d_in[3];
  const float* bk = (const float*)d_in[4];
  const float* wv = (const float*)d_in[5];
  const float* bv = (const float*)d_in[6];
  float* out = (float*)d_out;
  char* ws = (char*)d_ws;
  // ws layout (bytes): qb 8,388,608 | kb 8,388,608 | vt 8,388,608
  short* qb = (short*)ws;
  short* kb = (short*)(ws + 8388608);
  short* vt = (short*)(ws + 16777216);

  qkv_gemm<<<768, 256, 0, stream>>>(x, wq, wk, wv, bq, bk, bv, qb, kb, vt);
  attn_kernel<<<256, 512, 0, stream>>>(qb, kb, vt, out);
}